// Round 3
// baseline (886.395 us; speedup 1.0000x reference)
//
#include <hip/hip_runtime.h>
#include <hip/hip_bf16.h>

// Problem constants (fixed by setup_inputs)
#define TT    2209          // 47*47 relative-position table entries
#define NB    32            // batch
#define NH    16            // heads
#define ND    512           // RPB hidden dim
#define WH    24            // window height/width
#define NW    576           // 24*24 window tokens
#define NP    577           // NW + num_prefix_tokens(=1)
#define PLANE (NP * NP)     // 332929 floats per (b,h) output plane

// ---------------------------------------------------------------------------
// Stage 1: bias_t[b][h][t] = (relu((coords_table[t] + pos[b]) @ W1 + b1) @ W2)[h]
// Weights staged in LDS; all weight reads are wave-uniform broadcasts
// (conflict-free, ~2-4 cyc issue). Head-major output so stage 2's gathers
// for one plane are one contiguous 8.8 KB block.
// ---------------------------------------------------------------------------
__global__ __launch_bounds__(256) void cpb_mlp(
    const float* __restrict__ glob_pos,     // (1, 32, 4)
    const float* __restrict__ coords_table, // (2209, 2)
    const float* __restrict__ W1,           // (2, 512)
    const float* __restrict__ b1,           // (512,)
    const float* __restrict__ W2,           // (512, 16)
    float* __restrict__ bias_t)             // (32, 16, 2209) scratch
{
    __shared__ float sW13[ND][4];           // {W1row0, W1row1, b1, pad} — 8 KB
    __shared__ float sW2[ND][NH];           // 32 KB

    const int tid = threadIdx.x;
    for (int d = tid; d < ND; d += 256) {
        float4 v;
        v.x = W1[d];            // W1[0][d]
        v.y = W1[ND + d];       // W1[1][d]
        v.z = b1[d];
        v.w = 0.0f;
        *reinterpret_cast<float4*>(&sW13[d][0]) = v;
    }
    for (int i = tid; i < ND * NH / 4; i += 256) {
        reinterpret_cast<float4*>(&sW2[0][0])[i] =
            reinterpret_cast<const float4*>(W2)[i];
    }
    __syncthreads();

    const unsigned gid  = blockIdx.x * 256u + tid;
    const bool     live = gid < (unsigned)(NB * TT);
    const unsigned b    = live ? gid / TT : 0u;
    const unsigned t    = live ? gid - b * TT : 0u;

    // pos transform (per-batch; trivial)
    const float g0 = glob_pos[b * 4 + 0];
    const float g1 = glob_pos[b * 4 + 1];
    const float g2 = glob_pos[b * 4 + 2];
    const float g3 = glob_pos[b * 4 + 3];
    float px = g2 / g0 * 8.0f;
    float py = g3 / g1 * 8.0f;
    px = copysignf(log2f(fabsf(px) + 1.0f) * (1.0f / 3.0f), px) * 2.0f - 1.0f;
    py = copysignf(log2f(fabsf(py) + 1.0f) * (1.0f / 3.0f), py) * 2.0f - 1.0f;

    const float tx = coords_table[t * 2 + 0] + px;
    const float ty = coords_table[t * 2 + 1] + py;

    float acc[NH];
#pragma unroll
    for (int h = 0; h < NH; ++h) acc[h] = 0.0f;

#pragma unroll 1
    for (int d0 = 0; d0 < ND; d0 += 4) {
        float hv[4];
#pragma unroll
        for (int k = 0; k < 4; ++k) {
            const float4 w = *reinterpret_cast<const float4*>(&sW13[d0 + k][0]);
            hv[k] = fmaxf(fmaf(tx, w.x, fmaf(ty, w.y, w.z)), 0.0f);
        }
#pragma unroll
        for (int k = 0; k < 4; ++k) {
            const float4 w0 = *reinterpret_cast<const float4*>(&sW2[d0 + k][0]);
            const float4 w1 = *reinterpret_cast<const float4*>(&sW2[d0 + k][4]);
            const float4 w2 = *reinterpret_cast<const float4*>(&sW2[d0 + k][8]);
            const float4 w3 = *reinterpret_cast<const float4*>(&sW2[d0 + k][12]);
            acc[0]  = fmaf(hv[k], w0.x, acc[0]);   acc[1]  = fmaf(hv[k], w0.y, acc[1]);
            acc[2]  = fmaf(hv[k], w0.z, acc[2]);   acc[3]  = fmaf(hv[k], w0.w, acc[3]);
            acc[4]  = fmaf(hv[k], w1.x, acc[4]);   acc[5]  = fmaf(hv[k], w1.y, acc[5]);
            acc[6]  = fmaf(hv[k], w1.z, acc[6]);   acc[7]  = fmaf(hv[k], w1.w, acc[7]);
            acc[8]  = fmaf(hv[k], w2.x, acc[8]);   acc[9]  = fmaf(hv[k], w2.y, acc[9]);
            acc[10] = fmaf(hv[k], w2.z, acc[10]);  acc[11] = fmaf(hv[k], w2.w, acc[11]);
            acc[12] = fmaf(hv[k], w3.x, acc[12]);  acc[13] = fmaf(hv[k], w3.y, acc[13]);
            acc[14] = fmaf(hv[k], w3.z, acc[14]);  acc[15] = fmaf(hv[k], w3.w, acc[15]);
        }
    }

    if (live) {
#pragma unroll
        for (int h = 0; h < NH; ++h) {
            bias_t[(b * NH + h) * TT + t] = acc[h];
        }
    }
}

// ---------------------------------------------------------------------------
// Stage 2: out[b][h][i][j] = (i&&j) ? plane[(qh-kh+23)*47 + (qw-kw+23)] : 0
// One block per (plane, 2048-element chunk). The 8.8 KB plane is staged in
// LDS once; gathers come from LDS (consecutive-lane descending addresses ->
// conflict-free); the only VMEM is the pure streaming store.
// Scalar dword stores (plane base p*332929 is odd -> float4 would misalign);
// 64 lanes x 4 B = 256 B per instr, fully coalesced.
// ---------------------------------------------------------------------------
#define ELEMS 8
#define CHUNK (256 * ELEMS)                 // 2048
#define CPB   ((PLANE + CHUNK - 1) / CHUNK) // 163 chunks per plane

__global__ __launch_bounds__(256) void cpb_scatter(
    const float* __restrict__ bias_t, // (32, 16, 2209)
    float* __restrict__ out)          // (32, 16, 577, 577)
{
    __shared__ float sPlane[TT];      // 8836 B

    const unsigned bx  = blockIdx.x;
    const unsigned p   = bx / CPB;            // plane = b*16 + h
    const unsigned c   = bx - p * CPB;
    const unsigned tid = threadIdx.x;

    const float* __restrict__ plane = bias_t + (size_t)p * TT;
    for (unsigned idx = tid; idx < TT; idx += 256u) sPlane[idx] = plane[idx];
    __syncthreads();

    const unsigned cb = c * CHUNK;
    float* __restrict__ oplane = out + (size_t)p * PLANE;

#pragma unroll
    for (int k = 0; k < ELEMS; ++k) {
        const unsigned off = cb + tid + 256u * (unsigned)k;
        if (off < (unsigned)PLANE) {
            const unsigned i = off / NP;              // magic-mul
            const unsigned j = off - i * NP;
            float v = 0.0f;
            if (i != 0u && j != 0u) {
                const unsigned q  = i - 1u;
                const unsigned kk = j - 1u;
                const unsigned qh = q / WH,  qw = q - qh * WH;
                const unsigned kh = kk / WH, kw = kk - kh * WH;
                v = sPlane[(qh - kh + (WH - 1u)) * (2u * WH - 1u)
                           + (qw - kw + (WH - 1u))];
            }
            oplane[off] = v;
        }
    }
}

// ---------------------------------------------------------------------------
extern "C" void kernel_launch(void* const* d_in, const int* in_sizes, int n_in,
                              void* d_out, int out_size, void* d_ws, size_t ws_size,
                              hipStream_t stream)
{
    const float* glob_pos     = (const float*)d_in[0];
    const float* coords_table = (const float*)d_in[1];
    // d_in[2] = rpi — unused (index computed analytically in stage 2)
    const float* W1           = (const float*)d_in[3];
    const float* b1           = (const float*)d_in[4];
    const float* W2           = (const float*)d_in[5];
    // d_in[6] = num_prefix_tokens (always 1; NP/PLANE are compile-time)

    float* out    = (float*)d_out;
    float* bias_t = (float*)d_ws;   // 32*16*2209 floats = 4.5 MB scratch

    // Stage 1: 32*2209 = 70,688 threads
    const int n1 = NB * TT;
    const int blocks1 = (n1 + 255) / 256;
    cpb_mlp<<<blocks1, 256, 0, stream>>>(glob_pos, coords_table, W1, b1, W2, bias_t);

    // Stage 2: 512 planes x 163 chunks
    const unsigned blocks2 = (unsigned)NB * NH * CPB;
    cpb_scatter<<<blocks2, 256, 0, stream>>>(bias_t, out);
}

// Round 6
// 730.510 us; speedup vs baseline: 1.2134x; 1.2134x over previous
//
#include <hip/hip_runtime.h>
#include <hip/hip_bf16.h>

// Problem constants (fixed by setup_inputs)
#define TT    2209          // 47*47 relative-position table entries
#define NB    32            // batch
#define NH    16            // heads
#define ND    512           // RPB hidden dim
#define WH    24            // window height/width
#define NW    576           // 24*24 window tokens
#define NP    577           // NW + num_prefix_tokens(=1)
#define PLANE (NP * NP)     // 332929 floats per (b,h) output plane

// native clang vector type — required by __builtin_nontemporal_store
typedef float vfloat4 __attribute__((ext_vector_type(4)));

// ---------------------------------------------------------------------------
// Stage 1: bias_t[b][h][t] = (relu((coords_table[t] + pos[b]) @ W1 + b1) @ W2)[h]
// Weights staged in LDS; all weight reads are wave-uniform broadcasts
// (conflict-free). Head-major output so stage 2's gathers for one plane are
// one contiguous 8.8 KB block.  ~15 µs, VALU/LDS-issue bound.
// ---------------------------------------------------------------------------
__global__ __launch_bounds__(256) void cpb_mlp(
    const float* __restrict__ glob_pos,     // (1, 32, 4)
    const float* __restrict__ coords_table, // (2209, 2)
    const float* __restrict__ W1,           // (2, 512)
    const float* __restrict__ b1,           // (512,)
    const float* __restrict__ W2,           // (512, 16)
    float* __restrict__ bias_t)             // (32, 16, 2209) scratch
{
    __shared__ float sW13[ND][4];           // {W1row0, W1row1, b1, pad} — 8 KB
    __shared__ float sW2[ND][NH];           // 32 KB

    const int tid = threadIdx.x;
    for (int d = tid; d < ND; d += 256) {
        float4 v;
        v.x = W1[d];            // W1[0][d]
        v.y = W1[ND + d];       // W1[1][d]
        v.z = b1[d];
        v.w = 0.0f;
        *reinterpret_cast<float4*>(&sW13[d][0]) = v;
    }
    for (int i = tid; i < ND * NH / 4; i += 256) {
        reinterpret_cast<float4*>(&sW2[0][0])[i] =
            reinterpret_cast<const float4*>(W2)[i];
    }
    __syncthreads();

    const unsigned gid  = blockIdx.x * 256u + tid;
    const bool     live = gid < (unsigned)(NB * TT);
    const unsigned b    = live ? gid / TT : 0u;
    const unsigned t    = live ? gid - b * TT : 0u;

    const float g0 = glob_pos[b * 4 + 0];
    const float g1 = glob_pos[b * 4 + 1];
    const float g2 = glob_pos[b * 4 + 2];
    const float g3 = glob_pos[b * 4 + 3];
    float px = g2 / g0 * 8.0f;
    float py = g3 / g1 * 8.0f;
    px = copysignf(log2f(fabsf(px) + 1.0f) * (1.0f / 3.0f), px) * 2.0f - 1.0f;
    py = copysignf(log2f(fabsf(py) + 1.0f) * (1.0f / 3.0f), py) * 2.0f - 1.0f;

    const float tx = coords_table[t * 2 + 0] + px;
    const float ty = coords_table[t * 2 + 1] + py;

    float acc[NH];
#pragma unroll
    for (int h = 0; h < NH; ++h) acc[h] = 0.0f;

#pragma unroll 1
    for (int d0 = 0; d0 < ND; d0 += 4) {
        float hv[4];
#pragma unroll
        for (int k = 0; k < 4; ++k) {
            const float4 w = *reinterpret_cast<const float4*>(&sW13[d0 + k][0]);
            hv[k] = fmaxf(fmaf(tx, w.x, fmaf(ty, w.y, w.z)), 0.0f);
        }
#pragma unroll
        for (int k = 0; k < 4; ++k) {
            const float4 w0 = *reinterpret_cast<const float4*>(&sW2[d0 + k][0]);
            const float4 w1 = *reinterpret_cast<const float4*>(&sW2[d0 + k][4]);
            const float4 w2 = *reinterpret_cast<const float4*>(&sW2[d0 + k][8]);
            const float4 w3 = *reinterpret_cast<const float4*>(&sW2[d0 + k][12]);
            acc[0]  = fmaf(hv[k], w0.x, acc[0]);   acc[1]  = fmaf(hv[k], w0.y, acc[1]);
            acc[2]  = fmaf(hv[k], w0.z, acc[2]);   acc[3]  = fmaf(hv[k], w0.w, acc[3]);
            acc[4]  = fmaf(hv[k], w1.x, acc[4]);   acc[5]  = fmaf(hv[k], w1.y, acc[5]);
            acc[6]  = fmaf(hv[k], w1.z, acc[6]);   acc[7]  = fmaf(hv[k], w1.w, acc[7]);
            acc[8]  = fmaf(hv[k], w2.x, acc[8]);   acc[9]  = fmaf(hv[k], w2.y, acc[9]);
            acc[10] = fmaf(hv[k], w2.z, acc[10]);  acc[11] = fmaf(hv[k], w2.w, acc[11]);
            acc[12] = fmaf(hv[k], w3.x, acc[12]);  acc[13] = fmaf(hv[k], w3.y, acc[13]);
            acc[14] = fmaf(hv[k], w3.z, acc[14]);  acc[15] = fmaf(hv[k], w3.w, acc[15]);
        }
    }

    if (live) {
#pragma unroll
        for (int h = 0; h < NH; ++h) {
            bias_t[(b * NH + h) * TT + t] = acc[h];
        }
    }
}

// ---------------------------------------------------------------------------
// Stage 2: out[flat] — pure float4 nontemporal store stream (fill-like).
// Each block owns a contiguous 41,984-element flat range (spans at most one
// plane boundary); both touchable planes are staged in LDS once per block.
// idx computed analytically: (qh-kh+23)*47 + (qw-kw+23).
// ---------------------------------------------------------------------------
#define VPT   41u                       // float4 groups per thread
#define GPB   (256u * VPT)              // groups per block
#define EPB   (GPB * 4u)                // elements per block = 41984 (< PLANE)

__global__ __launch_bounds__(256) void cpb_scatter(
    const float* __restrict__ bias_t, // (32, 16, 2209)
    float* __restrict__ out)          // (32, 16, 577, 577) flat
{
    constexpr unsigned TOTAL = (unsigned)NB * NH * PLANE; // 170,459,648 (div 4)

    const unsigned bx    = blockIdx.x;
    const unsigned tid   = threadIdx.x;
    const unsigned ebase = bx * EPB;
    if (ebase >= TOTAL) return;                 // whole block OOB (uniform)

    __shared__ float sA[TT];                    // first plane this block touches
    __shared__ float sB[TT];                    // last plane (== first if no cross)

    const unsigned eend = min(ebase + EPB, TOTAL);
    const unsigned pA   = ebase / PLANE;
    const unsigned pB   = (eend - 1u) / PLANE;  // pA or pA+1, <= 511
    const float* __restrict__ plA = bias_t + (size_t)pA * TT;
    const float* __restrict__ plB = bias_t + (size_t)pB * TT;
    for (unsigned x = tid; x < (unsigned)TT; x += 256u) {
        sA[x] = plA[x];
        sB[x] = plB[x];
    }
    __syncthreads();

#pragma unroll 2
    for (unsigned k = 0; k < VPT; ++k) {
        const unsigned off = ebase + (k * 256u + tid) * 4u;
        if (off < TOTAL) {
            const unsigned p0   = off / PLANE;          // magic-mul
            const unsigned rem0 = off - p0 * PLANE;
            vfloat4 o;
#pragma unroll
            for (int d = 0; d < 4; ++d) {
                unsigned pp = p0;
                unsigned ee = rem0 + (unsigned)d;
                if (ee >= (unsigned)PLANE) { ee -= (unsigned)PLANE; ++pp; }
                const float* __restrict__ s = (pp == pA) ? sA : sB;
                const unsigned i = ee / NP;             // magic-mul
                const unsigned j = ee - i * NP;
                float v = 0.0f;
                if (i != 0u && j != 0u) {
                    const unsigned q  = i - 1u;
                    const unsigned kk = j - 1u;
                    const unsigned qh = q / WH,  qw = q - qh * WH;
                    const unsigned kh = kk / WH, kw = kk - kh * WH;
                    v = s[(qh - kh + (WH - 1u)) * (2u * WH - 1u)
                          + (qw - kw + (WH - 1u))];
                }
                o[d] = v;
            }
            __builtin_nontemporal_store(o, reinterpret_cast<vfloat4*>(out + off));
        }
    }
}

// ---------------------------------------------------------------------------
extern "C" void kernel_launch(void* const* d_in, const int* in_sizes, int n_in,
                              void* d_out, int out_size, void* d_ws, size_t ws_size,
                              hipStream_t stream)
{
    const float* glob_pos     = (const float*)d_in[0];
    const float* coords_table = (const float*)d_in[1];
    // d_in[2] = rpi — unused (index computed analytically in stage 2)
    const float* W1           = (const float*)d_in[3];
    const float* b1           = (const float*)d_in[4];
    const float* W2           = (const float*)d_in[5];
    // d_in[6] = num_prefix_tokens (always 1; NP/PLANE are compile-time)

    float* out    = (float*)d_out;
    float* bias_t = (float*)d_ws;   // 32*16*2209 floats = 4.5 MB scratch

    // Stage 1: 32*2209 = 70,688 threads
    const int n1 = NB * TT;
    const int blocks1 = (n1 + 255) / 256;
    cpb_mlp<<<blocks1, 256, 0, stream>>>(glob_pos, coords_table, W1, b1, W2, bias_t);

    // Stage 2: contiguous flat ranges, 41,984 elems / block
    constexpr unsigned TOTAL  = (unsigned)NB * NH * PLANE;
    const unsigned blocks2 = (TOTAL + EPB - 1u) / EPB;   // 4061
    cpb_scatter<<<blocks2, 256, 0, stream>>>(bias_t, out);
}